// Round 5
// baseline (959.758 us; speedup 1.0000x reference)
//
#include <hip/hip_runtime.h>

#define H 4096
#define O 4096
#define HO 8192
#define MAXLEN 15
#define NBLK 512

struct Args {
    const int* ids;
    const float* hidden;
    const float* eseq;
    const float* embW;
    const float* attW;
    const float* attb;
    const float* combW;
    const float* combB;
    const float* gihW;
    const float* gihB;
    const float* ghhW;
    const float* ghhB;
    const float* outW;
    const float* outB;
    float* out;
    float* ws;
};

__device__ __forceinline__ float dot4f(const float4 a, const float4 b) {
    return a.x * b.x + a.y * b.y + a.z * b.z + a.w * b.w;
}

#define XRED(v) { _Pragma("unroll") for (int o_ = 32; o_; o_ >>= 1) v += __shfl_xor(v, o_, 64); }

// Load a K=4096 x-slice into 16 resident float4 regs (64 VGPRs).
__device__ __forceinline__ void loadx16(const float* __restrict__ x, int lane, float4 xs[16]) {
    const float4* x4 = (const float4*)x;
    #pragma unroll
    for (int c = 0; c < 16; c++) xs[c] = x4[lane + c * 64];
}

// Two K=4096 weight rows against the resident x-slice: 32 independent loads,
// fully unrolled — compiler can keep a deep load pipeline (VGPR budget 256).
__device__ __forceinline__ void dot16x2(const float* __restrict__ w0,
                                        const float* __restrict__ w1,
                                        const float4 xs[16], int lane,
                                        float& s0, float& s1) {
    const float4* a4 = (const float4*)w0;
    const float4* b4 = (const float4*)w1;
    float x0 = 0.f, x1 = 0.f;
    #pragma unroll
    for (int c = 0; c < 16; c++) {
        x0 += dot4f(a4[lane + c * 64], xs[c]);
        x1 += dot4f(b4[lane + c * 64], xs[c]);
    }
    s0 += x0; s1 += x1;
}

// Global barrier: per-phase counter (no reset/sense needed; counters zeroed
// by k_zero each iteration). Agent-scope atomics + threadfence for cross-XCD
// visibility of plain stores.
__device__ __forceinline__ void gsync(unsigned* ctr) {
    __syncthreads();
    if (threadIdx.x == 0) {
        __threadfence();
        __hip_atomic_fetch_add(ctr, 1u, __ATOMIC_ACQ_REL, __HIP_MEMORY_SCOPE_AGENT);
        while (__hip_atomic_load(ctr, __ATOMIC_ACQUIRE, __HIP_MEMORY_SCOPE_AGENT) < NBLK)
            __builtin_amdgcn_s_sleep(2);
        __threadfence();
    }
    __syncthreads();
}

__global__ void k_zero(unsigned* c) { if (threadIdx.x < 16) c[threadIdx.x] = 0; }

// Persistent fused kernel: 512 blocks x 256 threads = 2048 waves.
// Wave gw owns output rows {gw, gw+2048} of every 4096-wide stage.
// gh gate pre-activations stay in registers from phase A to phase D.
__global__ __launch_bounds__(256, 2) void k_fused(Args a) {
    __shared__ float red[4];
    __shared__ float red2[4];
    unsigned* ctr   = (unsigned*)a.ws;          // [0..15]
    float* combined = a.ws + 64;                // 8192
    float* xbuf     = a.ws + 64 + 8192;         // 4096
    float* hbuf     = a.ws + 64 + 12288;        // 4096
    float* logits   = a.ws + 64 + 16384;        // 4096
    float* attlog   = a.ws + 64 + 20480;        // 16

    const int tid = threadIdx.x, lane = tid & 63, w4 = tid >> 6;
    const int gw = blockIdx.x * 4 + w4;         // 0..2047
    const int i0 = gw, i1 = gw + 2048;

    // ---- Phase A: gh = ghh_W @ h0 + b_hh for rows i0,i1 (regs) + att logits
    float hr0, hz0, hn0, hr1, hz1, hn1;
    {
        float4 hs[16];
        loadx16(a.hidden, lane, hs);
        float s00 = 0.f, s10 = 0.f, s01 = 0.f, s11 = 0.f, s02 = 0.f, s12 = 0.f;
        dot16x2(a.ghhW + (size_t)i0 * H,           a.ghhW + (size_t)i1 * H,           hs, lane, s00, s10);
        dot16x2(a.ghhW + (size_t)(i0 + H) * H,     a.ghhW + (size_t)(i1 + H) * H,     hs, lane, s01, s11);
        dot16x2(a.ghhW + (size_t)(i0 + 2 * H) * H, a.ghhW + (size_t)(i1 + 2 * H) * H, hs, lane, s02, s12);
        XRED(s00); XRED(s10); XRED(s01); XRED(s11); XRED(s02); XRED(s12);
        hr0 = s00 + a.ghhB[i0]; hz0 = s01 + a.ghhB[i0 + H]; hn0 = s02 + a.ghhB[i0 + 2 * H];
        hr1 = s10 + a.ghhB[i1]; hz1 = s11 + a.ghhB[i1 + H]; hn1 = s12 + a.ghhB[i1 + 2 * H];

        if (gw < MAXLEN) {
            const int id = a.ids[0];
            const float* ar = a.attW + (size_t)gw * HO;
            float4 es[16];
            loadx16(a.embW + (size_t)id * O, lane, es);
            float sa = 0.f, sb = 0.f;
            dot16x2(ar, ar + O, es, lane, sa, sb);   // sb uses es but is recomputed below
            // recompute hidden-half properly against hs
            sb = 0.f;
            {
                const float4* b4 = (const float4*)(ar + O);
                #pragma unroll
                for (int c = 0; c < 16; c++) sb += dot4f(b4[lane + c * 64], hs[c]);
            }
            float s = sa + sb;
            XRED(s);
            if (lane == 0) attlog[gw] = s + a.attb[gw];
        }
    }
    gsync(ctr + 0);

    // ---- Phase B: softmax(15) + combined = [emb | attw @ eseq]
    if (blockIdx.x < 32) {
        const int k = blockIdx.x * 256 + tid;   // 0..8191
        float l[MAXLEN];
        float m = -1e30f;
        #pragma unroll
        for (int j = 0; j < MAXLEN; j++) { l[j] = attlog[j]; m = fmaxf(m, l[j]); }
        float s = 0.f;
        #pragma unroll
        for (int j = 0; j < MAXLEN; j++) { l[j] = __expf(l[j] - m); s += l[j]; }
        const float inv = 1.f / s;
        if (k < O) {
            combined[k] = a.embW[(size_t)a.ids[0] * O + k];
            if (k < MAXLEN) a.out[8192 + k] = l[k] * inv;
        } else {
            const int kk = k - O;
            float acc = 0.f;
            #pragma unroll
            for (int j = 0; j < MAXLEN; j++) acc += l[j] * a.eseq[j * H + kk];
            combined[k] = acc * inv;
        }
    }
    gsync(ctr + 1);

    // ---- Phase C: x = relu(comb_W @ combined + b), rows i0,i1, K=8192
    {
        float s0 = 0.f, s1 = 0.f;
        #pragma unroll
        for (int hh = 0; hh < 2; hh++) {
            float4 xs[16];
            loadx16(combined + hh * 4096, lane, xs);
            dot16x2(a.combW + (size_t)i0 * HO + hh * 4096,
                    a.combW + (size_t)i1 * HO + hh * 4096, xs, lane, s0, s1);
        }
        XRED(s0); XRED(s1);
        if (lane == 0) {
            xbuf[i0] = fmaxf(s0 + a.combB[i0], 0.f);
            xbuf[i1] = fmaxf(s1 + a.combB[i1], 0.f);
        }
    }
    gsync(ctr + 2);

    // ---- Phase D: gi = gih_W @ x rows i0,i1 + gate math with register gh
    {
        float4 xs[16];
        loadx16(xbuf, lane, xs);
        float s00 = 0.f, s10 = 0.f, s01 = 0.f, s11 = 0.f, s02 = 0.f, s12 = 0.f;
        dot16x2(a.gihW + (size_t)i0 * H,           a.gihW + (size_t)i1 * H,           xs, lane, s00, s10);
        dot16x2(a.gihW + (size_t)(i0 + H) * H,     a.gihW + (size_t)(i1 + H) * H,     xs, lane, s01, s11);
        dot16x2(a.gihW + (size_t)(i0 + 2 * H) * H, a.gihW + (size_t)(i1 + 2 * H) * H, xs, lane, s02, s12);
        XRED(s00); XRED(s10); XRED(s01); XRED(s11); XRED(s02); XRED(s12);
        if (lane == 0) {
            float r0 = 1.f / (1.f + __expf(-(s00 + a.gihB[i0] + hr0)));
            float z0 = 1.f / (1.f + __expf(-(s01 + a.gihB[i0 + H] + hz0)));
            float n0 = tanhf(s02 + a.gihB[i0 + 2 * H] + r0 * hn0);
            float h0 = (1.f - z0) * n0 + z0 * a.hidden[i0];
            hbuf[i0] = h0; a.out[4096 + i0] = h0;
            float r1 = 1.f / (1.f + __expf(-(s10 + a.gihB[i1] + hr1)));
            float z1 = 1.f / (1.f + __expf(-(s11 + a.gihB[i1 + H] + hz1)));
            float n1 = tanhf(s12 + a.gihB[i1 + 2 * H] + r1 * hn1);
            float h1 = (1.f - z1) * n1 + z1 * a.hidden[i1];
            hbuf[i1] = h1; a.out[4096 + i1] = h1;
        }
    }
    gsync(ctr + 3);

    // ---- Phase E: logits = out_W @ h + out_b, rows i0,i1
    {
        float4 xs[16];
        loadx16(hbuf, lane, xs);
        float s0 = 0.f, s1 = 0.f;
        dot16x2(a.outW + (size_t)i0 * H, a.outW + (size_t)i1 * H, xs, lane, s0, s1);
        XRED(s0); XRED(s1);
        if (lane == 0) {
            logits[i0] = s0 + a.outB[i0];
            logits[i1] = s1 + a.outB[i1];
        }
    }
    gsync(ctr + 4);

    // ---- Phase F: log_softmax (block 0)
    if (blockIdx.x == 0) {
        float m = -1e30f;
        for (int k = tid; k < O; k += 256) m = fmaxf(m, logits[k]);
        #pragma unroll
        for (int o_ = 32; o_; o_ >>= 1) m = fmaxf(m, __shfl_xor(m, o_, 64));
        if (lane == 0) red[w4] = m;
        __syncthreads();
        m = fmaxf(fmaxf(red[0], red[1]), fmaxf(red[2], red[3]));
        float s = 0.f;
        for (int k = tid; k < O; k += 256) s += __expf(logits[k] - m);
        XRED(s);
        if (lane == 0) red2[w4] = s;
        __syncthreads();
        const float lse = m + logf(red2[0] + red2[1] + red2[2] + red2[3]);
        for (int k = tid; k < O; k += 256) a.out[k] = logits[k] - lse;
    }
}

extern "C" void kernel_launch(void* const* d_in, const int* in_sizes, int n_in,
                              void* d_out, int out_size, void* d_ws, size_t ws_size,
                              hipStream_t stream) {
    Args a;
    a.ids    = (const int*)d_in[0];
    a.hidden = (const float*)d_in[1];
    // d_in[2] (e_output) unused by the reference
    a.eseq   = (const float*)d_in[3];
    a.embW   = (const float*)d_in[4];
    a.attW   = (const float*)d_in[5];
    a.attb   = (const float*)d_in[6];
    a.combW  = (const float*)d_in[7];
    a.combB  = (const float*)d_in[8];
    a.gihW   = (const float*)d_in[9];
    a.ghhW   = (const float*)d_in[10];
    a.gihB   = (const float*)d_in[11];
    a.ghhB   = (const float*)d_in[12];
    a.outW   = (const float*)d_in[13];
    a.outB   = (const float*)d_in[14];
    a.out    = (float*)d_out;   // [log_softmax(4096) | h_new(4096) | att_w(15)]
    a.ws     = (float*)d_ws;

    k_zero<<<1, 64, 0, stream>>>((unsigned*)d_ws);
    k_fused<<<NBLK, 256, 0, stream>>>(a);
}

// Round 6
// 568.980 us; speedup vs baseline: 1.6868x; 1.6868x over previous
//
#include <hip/hip_runtime.h>

#define H 4096
#define O 4096
#define HO 8192
#define MAXLEN 15

__device__ __forceinline__ float dot4f(const float4 a, const float4 b) {
    return a.x * b.x + a.y * b.y + a.z * b.z + a.w * b.w;
}

#define XRED(v) { _Pragma("unroll") for (int o_ = 32; o_; o_ >>= 1) v += __shfl_xor(v, o_, 64); }

// Split-K GEMV block: 256 threads = 4 waves. K = 1024*C (C=4 -> 4096, C=8 -> 8192).
// Wave w owns K-slice [w*256*C, (w+1)*256*C); its x-slice lives in C float4 regs.
// Block computes R consecutive rows; weight reads are pure sequential streams
// (no interleaved x traffic), block footprint = R rows contiguous.
template<int C, int R, bool RELU>
__device__ __forceinline__ void gemv_rows(const float* __restrict__ W,
                                          const float* __restrict__ x,
                                          const float* __restrict__ bias,
                                          float* __restrict__ y,
                                          int row0) {
    __shared__ float spart[4][R];
    const int tid = threadIdx.x, lane = tid & 63, w = tid >> 6;
    const int K4 = 256 * C;                   // float4 per row
    const float4* x4 = (const float4*)x;
    float4 xs[C];
    #pragma unroll
    for (int c = 0; c < C; c++) xs[c] = x4[w * (64 * C) + lane + 64 * c];

    float acc[R];
    const float4* Wr = (const float4*)W + (size_t)row0 * K4 + w * (64 * C) + lane;
    #pragma unroll
    for (int r = 0; r < R; r++) {
        const float4* wrow = Wr + (size_t)r * K4;
        float s = 0.f;
        #pragma unroll
        for (int c = 0; c < C; c++) s += dot4f(wrow[64 * c], xs[c]);
        acc[r] = s;
    }
    #pragma unroll
    for (int r = 0; r < R; r++) { XRED(acc[r]); }
    if (lane == 0) {
        #pragma unroll
        for (int r = 0; r < R; r++) spart[w][r] = acc[r];
    }
    __syncthreads();
    if (tid < R) {
        float v = spart[0][tid] + spart[1][tid] + spart[2][tid] + spart[3][tid] + bias[row0 + tid];
        y[row0 + tid] = RELU ? fmaxf(v, 0.f) : v;
    }
}

// K1a: attention logits, one block per attention row.
__global__ __launch_bounds__(1024) void k_attlogit(const int* __restrict__ ids,
                                                   const float* __restrict__ hidden,
                                                   const float* __restrict__ embW,
                                                   const float* __restrict__ attW,
                                                   const float* __restrict__ attb,
                                                   float* __restrict__ attlog) {
    __shared__ float sred[16];
    const int tid = threadIdx.x, lane = tid & 63, wave = tid >> 6;
    const int j = blockIdx.x;
    const float* emb = embW + (size_t)ids[0] * O;
    const float4* w4 = (const float4*)(attW + (size_t)j * (H + O));
    const float4* e4 = (const float4*)emb;
    const float4* h4 = (const float4*)hidden;

    float4 wv0 = w4[tid];
    float4 xv0 = e4[tid];
    float4 wv1 = w4[tid + 1024];
    float4 xv1 = h4[tid];
    float acc = dot4f(wv0, xv0) + dot4f(wv1, xv1);
    XRED(acc);
    if (lane == 0) sred[wave] = acc;
    __syncthreads();
    if (tid == 0) {
        float s = 0.f;
        #pragma unroll
        for (int w = 0; w < 16; w++) s += sred[w];
        attlog[j] = s + attb[j];
    }
}

// K1b: softmax(15) per-thread + att_applied + emb copy into combined.
__global__ __launch_bounds__(256) void k_attapply(const int* __restrict__ ids,
                                                  const float* __restrict__ embW,
                                                  const float* __restrict__ attlog,
                                                  const float* __restrict__ eseq,
                                                  float* __restrict__ combined,
                                                  float* __restrict__ out_attw) {
    const int k = blockIdx.x * 256 + threadIdx.x;   // 0..4095
    float l[MAXLEN];
    float m = -1e30f;
    #pragma unroll
    for (int j = 0; j < MAXLEN; j++) { l[j] = attlog[j]; m = fmaxf(m, l[j]); }
    float s = 0.f;
    #pragma unroll
    for (int j = 0; j < MAXLEN; j++) { l[j] = __expf(l[j] - m); s += l[j]; }
    const float inv = 1.f / s;

    float acc = 0.f;
    #pragma unroll
    for (int j = 0; j < MAXLEN; j++) acc += l[j] * eseq[j * H + k];
    combined[O + k] = acc * inv;
    combined[k] = embW[(size_t)ids[0] * O + k];
    if (blockIdx.x == 0 && threadIdx.x < MAXLEN) out_attw[threadIdx.x] = l[threadIdx.x] * inv;
}

// gh = ghh_W @ h0 + b_hh : 12288 rows, K=4096, 16 rows/block -> 768 blocks
__global__ __launch_bounds__(256) void k_ghh(const float* __restrict__ W,
                                             const float* __restrict__ b,
                                             const float* __restrict__ x,
                                             float* __restrict__ y) {
    gemv_rows<4, 16, false>(W, x, b, y, blockIdx.x * 16);
}

// x = relu(comb_W @ combined + b) : 4096 rows, K=8192, 8 rows/block -> 512 blocks
__global__ __launch_bounds__(256) void k_comb(const float* __restrict__ W,
                                              const float* __restrict__ b,
                                              const float* __restrict__ x,
                                              float* __restrict__ y) {
    gemv_rows<8, 8, true>(W, x, b, y, blockIdx.x * 8);
}

// gi = gih_W @ x + b_ih : 12288 rows, K=4096 -> 768 blocks
__global__ __launch_bounds__(256) void k_gih(const float* __restrict__ W,
                                             const float* __restrict__ b,
                                             const float* __restrict__ x,
                                             float* __restrict__ y) {
    gemv_rows<4, 16, false>(W, x, b, y, blockIdx.x * 16);
}

// logits = out_W @ h + out_b : 4096 rows, K=4096, 8 rows/block -> 512 blocks
__global__ __launch_bounds__(256) void k_outw(const float* __restrict__ W,
                                              const float* __restrict__ b,
                                              const float* __restrict__ x,
                                              float* __restrict__ y) {
    gemv_rows<4, 8, false>(W, x, b, y, blockIdx.x * 8);
}

// elementwise GRU gate math
__global__ __launch_bounds__(256) void k_gate(const float* __restrict__ gi,
                                              const float* __restrict__ gh,
                                              const float* __restrict__ hidden,
                                              float* __restrict__ hout,
                                              float* __restrict__ out_h) {
    const int i = blockIdx.x * 256 + threadIdx.x;   // 0..4095
    float r = 1.f / (1.f + __expf(-(gi[i] + gh[i])));
    float z = 1.f / (1.f + __expf(-(gi[i + H] + gh[i + H])));
    float n = tanhf(gi[i + 2 * H] + r * gh[i + 2 * H]);
    float h = (1.f - z) * n + z * hidden[i];
    hout[i] = h;
    out_h[i] = h;
}

// log_softmax over 4096 logits
__global__ __launch_bounds__(1024) void k_lsm(const float* __restrict__ logits,
                                              float* __restrict__ out) {
    __shared__ float red[16];
    __shared__ float red2[16];
    const int tid = threadIdx.x, lane = tid & 63, wave = tid >> 6;
    float m = -1e30f;
    for (int k = tid; k < O; k += 1024) m = fmaxf(m, logits[k]);
    #pragma unroll
    for (int off = 32; off; off >>= 1) m = fmaxf(m, __shfl_xor(m, off, 64));
    if (lane == 0) red[wave] = m;
    __syncthreads();
    if (tid == 0) {
        float mm = -1e30f;
        for (int j = 0; j < 16; j++) mm = fmaxf(mm, red[j]);
        red[0] = mm;
    }
    __syncthreads();
    m = red[0];
    float s = 0.f;
    for (int k = tid; k < O; k += 1024) s += __expf(logits[k] - m);
    XRED(s);
    if (lane == 0) red2[wave] = s;
    __syncthreads();
    if (tid == 0) {
        float ss = 0.f;
        for (int j = 0; j < 16; j++) ss += red2[j];
        red2[0] = m + logf(ss);
    }
    __syncthreads();
    float lse = red2[0];
    for (int k = tid; k < O; k += 1024) out[k] = logits[k] - lse;
}

extern "C" void kernel_launch(void* const* d_in, const int* in_sizes, int n_in,
                              void* d_out, int out_size, void* d_ws, size_t ws_size,
                              hipStream_t stream) {
    const int*   ids    = (const int*)d_in[0];
    const float* hidden = (const float*)d_in[1];
    // d_in[2] (e_output) unused by the reference
    const float* eseq   = (const float*)d_in[3];
    const float* embW   = (const float*)d_in[4];
    const float* attW   = (const float*)d_in[5];
    const float* attb   = (const float*)d_in[6];
    const float* combW  = (const float*)d_in[7];
    const float* combB  = (const float*)d_in[8];
    const float* gihW   = (const float*)d_in[9];
    const float* ghhW   = (const float*)d_in[10];
    const float* gihB   = (const float*)d_in[11];
    const float* ghhB   = (const float*)d_in[12];
    const float* outW   = (const float*)d_in[13];
    const float* outB   = (const float*)d_in[14];
    float* out = (float*)d_out;   // [log_softmax(4096) | h_new(4096) | att_w(15)]

    float* ws       = (float*)d_ws;
    float* combined = ws;              // 8192
    float* xbuf     = ws + 8192;       // 4096
    float* ghbuf    = ws + 12288;      // 12288
    float* gibuf    = ws + 24576;      // 12288
    float* hbuf     = ws + 36864;      // 4096
    float* logits   = ws + 40960;      // 4096
    float* attlog   = ws + 45056;      // 16

    k_attlogit<<<MAXLEN, 1024, 0, stream>>>(ids, hidden, embW, attW, attb, attlog);
    k_attapply<<<16,     256,  0, stream>>>(ids, embW, attlog, eseq, combined, out + 8192);
    k_ghh     <<<768,    256,  0, stream>>>(ghhW, ghhB, hidden, ghbuf);
    k_comb    <<<512,    256,  0, stream>>>(combW, combB, combined, xbuf);
    k_gih     <<<768,    256,  0, stream>>>(gihW, gihB, xbuf, gibuf);
    k_gate    <<<16,     256,  0, stream>>>(gibuf, ghbuf, hidden, hbuf, out + 4096);
    k_outw    <<<512,    256,  0, stream>>>(outW, outB, hbuf, logits);
    k_lsm     <<<1,      1024, 0, stream>>>(logits, out);
}

// Round 7
// 565.534 us; speedup vs baseline: 1.6971x; 1.0061x over previous
//
#include <hip/hip_runtime.h>

#define H 4096
#define O 4096
#define HO 8192
#define MAXLEN 15

typedef float v4f __attribute__((ext_vector_type(4)));

__device__ __forceinline__ float dot4f(const v4f a, const v4f b) {
    return a.x * b.x + a.y * b.y + a.z * b.z + a.w * b.w;
}

#define XRED(v) { _Pragma("unroll") for (int o_ = 32; o_; o_ >>= 1) v += __shfl_xor(v, o_, 64); }

// One K-sliced row-dot: wave's x-slice resident in xs[C]; weight row streamed,
// optionally non-temporal (nt flag -> no L2/L3 allocation).
template<int C, bool NT>
__device__ __forceinline__ float rowdot(const v4f* __restrict__ wrow, const v4f xs[C]) {
    float s = 0.f;
    #pragma unroll
    for (int c = 0; c < C; c++) {
        v4f wv = NT ? __builtin_nontemporal_load(&wrow[64 * c]) : wrow[64 * c];
        s += dot4f(wv, xs[c]);
    }
    return s;
}

// Split-K GEMV: 256 threads = 4 waves, wave w owns K-slice [w*1024*C/4 ...).
// Block computes R consecutive rows of W (K = 1024*C floats).
template<int C, int R, bool RELU, bool NT>
__global__ __launch_bounds__(256) void k_gemv(const float* __restrict__ W,
                                              const float* __restrict__ bias,
                                              const float* __restrict__ x,
                                              float* __restrict__ y) {
    __shared__ float spart[4][R];
    const int tid = threadIdx.x, lane = tid & 63, w = tid >> 6;
    const int row0 = blockIdx.x * R;
    const int K4 = 256 * C;                 // float4 per row
    const v4f* x4 = (const v4f*)x;
    v4f xs[C];
    #pragma unroll
    for (int c = 0; c < C; c++) xs[c] = x4[w * (64 * C) + lane + 64 * c];

    const v4f* Wb = (const v4f*)W + (size_t)row0 * K4 + w * (64 * C) + lane;
    float acc[R];
    #pragma unroll
    for (int r = 0; r < R; r++) acc[r] = rowdot<C, NT>(Wb + (size_t)r * K4, xs);
    #pragma unroll
    for (int r = 0; r < R; r++) { XRED(acc[r]); }
    if (lane == 0) {
        #pragma unroll
        for (int r = 0; r < R; r++) spart[w][r] = acc[r];
    }
    __syncthreads();
    if (tid < R) {
        float v = spart[0][tid] + spart[1][tid] + spart[2][tid] + spart[3][tid] + bias[row0 + tid];
        y[row0 + tid] = RELU ? fmaxf(v, 0.f) : v;
    }
}

// gi = gih_W @ x for 8 hidden units (3 gate rows each, NT weights) + gate math
// fused in the epilogue. 512 blocks x 8 units.
__global__ __launch_bounds__(256) void k_gigate(const float* __restrict__ gihW,
                                                const float* __restrict__ gihB,
                                                const float* __restrict__ x,
                                                const float* __restrict__ gh,
                                                const float* __restrict__ hidden,
                                                float* __restrict__ hout,
                                                float* __restrict__ out_h) {
    __shared__ float spart[4][24];
    const int tid = threadIdx.x, lane = tid & 63, w = tid >> 6;
    const int u0 = blockIdx.x * 8;
    const int K4 = 1024;                    // K=4096 -> 1024 float4
    const v4f* x4 = (const v4f*)x;
    v4f xs[4];
    #pragma unroll
    for (int c = 0; c < 4; c++) xs[c] = x4[w * 256 + lane + 64 * c];

    float acc[3][8];
    #pragma unroll
    for (int g = 0; g < 3; g++) {
        const v4f* Wb = (const v4f*)gihW + ((size_t)g * H + u0) * K4 + w * 256 + lane;
        #pragma unroll
        for (int r = 0; r < 8; r++) acc[g][r] = rowdot<4, true>(Wb + (size_t)r * K4, xs);
    }
    #pragma unroll
    for (int g = 0; g < 3; g++) {
        #pragma unroll
        for (int r = 0; r < 8; r++) { XRED(acc[g][r]); }
    }
    if (lane == 0) {
        #pragma unroll
        for (int g = 0; g < 3; g++)
            #pragma unroll
            for (int r = 0; r < 8; r++) spart[w][g * 8 + r] = acc[g][r];
    }
    __syncthreads();
    if (tid < 8) {
        const int u = u0 + tid;
        float gir = spart[0][tid]      + spart[1][tid]      + spart[2][tid]      + spart[3][tid]      + gihB[u];
        float giz = spart[0][8 + tid]  + spart[1][8 + tid]  + spart[2][8 + tid]  + spart[3][8 + tid]  + gihB[u + H];
        float gin = spart[0][16 + tid] + spart[1][16 + tid] + spart[2][16 + tid] + spart[3][16 + tid] + gihB[u + 2 * H];
        float r = 1.f / (1.f + __expf(-(gir + gh[u])));
        float z = 1.f / (1.f + __expf(-(giz + gh[u + H])));
        float n = tanhf(gin + r * gh[u + 2 * H]);
        float h = (1.f - z) * n + z * hidden[u];
        hout[u] = h;
        out_h[u] = h;
    }
}

// attention logits, one block per attention row.
__global__ __launch_bounds__(1024) void k_attlogit(const int* __restrict__ ids,
                                                   const float* __restrict__ hidden,
                                                   const float* __restrict__ embW,
                                                   const float* __restrict__ attW,
                                                   const float* __restrict__ attb,
                                                   float* __restrict__ attlog) {
    __shared__ float sred[16];
    const int tid = threadIdx.x, lane = tid & 63, wave = tid >> 6;
    const int j = blockIdx.x;
    const float* emb = embW + (size_t)ids[0] * O;
    const v4f* w4 = (const v4f*)(attW + (size_t)j * (H + O));
    const v4f* e4 = (const v4f*)emb;
    const v4f* h4 = (const v4f*)hidden;

    float acc = dot4f(w4[tid], e4[tid]) + dot4f(w4[tid + 1024], h4[tid]);
    XRED(acc);
    if (lane == 0) sred[wave] = acc;
    __syncthreads();
    if (tid == 0) {
        float s = 0.f;
        #pragma unroll
        for (int w = 0; w < 16; w++) s += sred[w];
        attlog[j] = s + attb[j];
    }
}

// softmax(15) per-thread + att_applied + emb copy into combined.
__global__ __launch_bounds__(256) void k_attapply(const int* __restrict__ ids,
                                                  const float* __restrict__ embW,
                                                  const float* __restrict__ attlog,
                                                  const float* __restrict__ eseq,
                                                  float* __restrict__ combined,
                                                  float* __restrict__ out_attw) {
    const int k = blockIdx.x * 256 + threadIdx.x;   // 0..4095
    float l[MAXLEN];
    float m = -1e30f;
    #pragma unroll
    for (int j = 0; j < MAXLEN; j++) { l[j] = attlog[j]; m = fmaxf(m, l[j]); }
    float s = 0.f;
    #pragma unroll
    for (int j = 0; j < MAXLEN; j++) { l[j] = __expf(l[j] - m); s += l[j]; }
    const float inv = 1.f / s;

    float acc = 0.f;
    #pragma unroll
    for (int j = 0; j < MAXLEN; j++) acc += l[j] * eseq[j * H + k];
    combined[O + k] = acc * inv;
    combined[k] = embW[(size_t)ids[0] * O + k];
    if (blockIdx.x == 0 && threadIdx.x < MAXLEN) out_attw[threadIdx.x] = l[threadIdx.x] * inv;
}

// log_softmax over 4096 logits
__global__ __launch_bounds__(1024) void k_lsm(const float* __restrict__ logits,
                                              float* __restrict__ out) {
    __shared__ float red[16];
    __shared__ float red2[16];
    const int tid = threadIdx.x, lane = tid & 63, wave = tid >> 6;
    float m = -1e30f;
    for (int k = tid; k < O; k += 1024) m = fmaxf(m, logits[k]);
    #pragma unroll
    for (int off = 32; off; off >>= 1) m = fmaxf(m, __shfl_xor(m, off, 64));
    if (lane == 0) red[wave] = m;
    __syncthreads();
    if (tid == 0) {
        float mm = -1e30f;
        for (int j = 0; j < 16; j++) mm = fmaxf(mm, red[j]);
        red[0] = mm;
    }
    __syncthreads();
    m = red[0];
    float s = 0.f;
    for (int k = tid; k < O; k += 1024) s += __expf(logits[k] - m);
    XRED(s);
    if (lane == 0) red2[wave] = s;
    __syncthreads();
    if (tid == 0) {
        float ss = 0.f;
        for (int j = 0; j < 16; j++) ss += red2[j];
        red2[0] = m + logf(ss);
    }
    __syncthreads();
    float lse = red2[0];
    for (int k = tid; k < O; k += 1024) out[k] = logits[k] - lse;
}

extern "C" void kernel_launch(void* const* d_in, const int* in_sizes, int n_in,
                              void* d_out, int out_size, void* d_ws, size_t ws_size,
                              hipStream_t stream) {
    const int*   ids    = (const int*)d_in[0];
    const float* hidden = (const float*)d_in[1];
    // d_in[2] (e_output) unused by the reference
    const float* eseq   = (const float*)d_in[3];
    const float* embW   = (const float*)d_in[4];
    const float* attW   = (const float*)d_in[5];
    const float* attb   = (const float*)d_in[6];
    const float* combW  = (const float*)d_in[7];
    const float* combB  = (const float*)d_in[8];
    const float* gihW   = (const float*)d_in[9];
    const float* ghhW   = (const float*)d_in[10];
    const float* gihB   = (const float*)d_in[11];
    const float* ghhB   = (const float*)d_in[12];
    const float* outW   = (const float*)d_in[13];
    const float* outB   = (const float*)d_in[14];
    float* out = (float*)d_out;   // [log_softmax(4096) | h_new(4096) | att_w(15)]

    float* ws       = (float*)d_ws;
    float* combined = ws;              // 8192
    float* xbuf     = ws + 8192;       // 4096
    float* ghbuf    = ws + 12288;      // 12288
    float* hbuf     = ws + 24576;      // 4096
    float* logits   = ws + 28672;      // 4096
    float* attlog   = ws + 32768;      // 16

    k_attlogit<<<MAXLEN, 1024, 0, stream>>>(ids, hidden, embW, attW, attb, attlog);
    k_attapply<<<16,     256,  0, stream>>>(ids, embW, attlog, eseq, combined, out + 8192);
    // ghh: NT weights (A/B treatment), 12288 rows K=4096, 16 rows/block
    k_gemv<4, 16, false, true> <<<768, 256, 0, stream>>>(ghhW, ghhB, hidden, ghbuf);
    // comb: cached weights (A/B control), 4096 rows K=8192, 8 rows/block
    k_gemv<8, 8,  true,  false><<<512, 256, 0, stream>>>(combW, combB, combined, xbuf);
    // gih + gate math fused, NT weights
    k_gigate<<<512, 256, 0, stream>>>(gihW, gihB, xbuf, ghbuf, hidden, hbuf, out + 4096);
    // out: cached weights (A/B control), 4096 rows K=4096, 8 rows/block
    k_gemv<4, 8,  false, false><<<512, 256, 0, stream>>>(outW, outB, hbuf, logits);
    k_lsm<<<1, 1024, 0, stream>>>(logits, out);
}